// Round 2
// baseline (3788.882 us; speedup 1.0000x reference)
//
#include <hip/hip_runtime.h>
#include <hip/hip_bf16.h>
#include <hip/hip_cooperative_groups.h>
#include <math.h>

namespace cg = cooperative_groups;

// Problem dims (fixed)
#define B   64
#define NN  196
#define HH  512
#define EE  512
#define AA  512
#define VV  20000
#define LL  20

typedef __attribute__((ext_vector_type(8))) short bf16x8;
typedef __attribute__((ext_vector_type(4))) float floatx4;

__device__ __forceinline__ float tanh_fast(float x) {
  float e2 = __expf(2.f * x);
  return 1.f - 2.f / (e2 + 1.f);
}
__device__ __forceinline__ float sigmoid_fast(float x) {
  return 1.f / (1.f + __expf(-x));
}
__device__ __forceinline__ float bf2f(unsigned short u) {
  return __uint_as_float(((unsigned)u) << 16);
}
__device__ __forceinline__ unsigned short f2bf(float v) {
  __hip_bfloat16 h = __float2bfloat16(v);
  return *reinterpret_cast<unsigned short*>(&h);
}

// ---------------------------------------------------------------------------
// bf16 MFMA GEMM: C[M,N] = Xb[M,K](bf16) @ Wb[N,K](bf16)^T + bias
// 128x128 tile, BK=32, 256 threads = 4 waves, each wave 64x64 via 16 MFMAs.
// gridMX: 0 -> (x=n-tiles, y=m-tiles); 1 -> (x=m-tiles, y=n-tiles)
//   gridMX=1 makes consecutive blocks share the same B-panel (n-tile), so a
//   huge B matrix (fcWb, 20.6 MB) is fetched ~once instead of ~5x.
// outMode==0: fp32 C[m*ldC+n]
// outMode==1: logits scatter out[b, t+1, n] with m = t*64 + b.
// outMode==2: bf16 store ((ushort*)C)[m*ldC+n]
// ---------------------------------------------------------------------------
__global__ __launch_bounds__(256) void gemm_mfma_bt(
    const unsigned short* __restrict__ Xb, const unsigned short* __restrict__ Wb,
    const float* __restrict__ bias, float* __restrict__ C,
    int M, int N, int K, int ldC, int outMode, int gridMX) {
  __shared__ unsigned short As[128 * 32];
  __shared__ unsigned short Bs[128 * 32];
  const int tid = threadIdx.x;
  const int lane = tid & 63;
  const int l15 = lane & 15;
  const int q = lane >> 4;        // quad 0..3
  const int wv = tid >> 6;        // wave 0..3
  const int wm = (wv >> 1) * 64;  // wave m-offset in tile
  const int wn = (wv & 1) * 64;   // wave n-offset in tile
  const int mBase = (gridMX ? blockIdx.x : blockIdx.y) * 128;
  const int nBase = (gridMX ? blockIdx.y : blockIdx.x) * 128;

  const int c0 = tid, c1 = tid + 256;
  const int r0 = c0 >> 2, o0 = (c0 & 3) * 8;
  const int r1 = c1 >> 2, o1 = (c1 & 3) * 8;

  floatx4 zero = {0.f, 0.f, 0.f, 0.f};
  floatx4 acc[4][4];
#pragma unroll
  for (int i = 0; i < 4; ++i)
#pragma unroll
    for (int j = 0; j < 4; ++j) acc[i][j] = zero;

  for (int k0 = 0; k0 < K; k0 += 32) {
    uint4 a0 = *(const uint4*)(Xb + (size_t)(mBase + r0) * K + k0 + o0);
    uint4 a1 = *(const uint4*)(Xb + (size_t)(mBase + r1) * K + k0 + o1);
    uint4 b0 = *(const uint4*)(Wb + (size_t)(nBase + r0) * K + k0 + o0);
    uint4 b1 = *(const uint4*)(Wb + (size_t)(nBase + r1) * K + k0 + o1);
    __syncthreads();
    *(uint4*)&As[c0 * 8] = a0;
    *(uint4*)&As[c1 * 8] = a1;
    *(uint4*)&Bs[c0 * 8] = b0;
    *(uint4*)&Bs[c1 * 8] = b1;
    __syncthreads();
    bf16x8 af[4], bfv[4];
#pragma unroll
    for (int i = 0; i < 4; ++i)
      af[i] = *(const bf16x8*)&As[(wm + i * 16 + l15) * 32 + q * 8];
#pragma unroll
    for (int j = 0; j < 4; ++j)
      bfv[j] = *(const bf16x8*)&Bs[(wn + j * 16 + l15) * 32 + q * 8];
#pragma unroll
    for (int i = 0; i < 4; ++i)
#pragma unroll
      for (int j = 0; j < 4; ++j)
        acc[i][j] = __builtin_amdgcn_mfma_f32_16x16x32_bf16(af[i], bfv[j],
                                                            acc[i][j], 0, 0, 0);
  }

#pragma unroll
  for (int i = 0; i < 4; ++i) {
#pragma unroll
    for (int j = 0; j < 4; ++j) {
#pragma unroll
      for (int p = 0; p < 4; ++p) {
        int m = mBase + wm + i * 16 + q * 4 + p;
        int n = nBase + wn + j * 16 + l15;
        if (m < M && n < N) {
          float v = acc[i][j][p];
          if (bias) v += bias[n];
          if (outMode == 1) {
            size_t idx = (size_t)(m & 63) * ((size_t)LL * VV) +
                         (size_t)((m >> 6) + 1) * VV + n;
            C[idx] = v;
          } else if (outMode == 2) {
            ((unsigned short*)C)[(size_t)m * ldC + n] = f2bf(v);
          } else {
            C[(size_t)m * ldC + n] = v;
          }
        }
      }
    }
  }
}

// ---------------------------------------------------------------------------
// fp32 -> bf16 conversion with optional row padding (zero fill) and stride.
// ---------------------------------------------------------------------------
__global__ __launch_bounds__(256) void convert_pad(
    const float* __restrict__ src, unsigned short* __restrict__ dst,
    int srcRows, int dstRows, int srcStride, int colOff) {
  int idx = blockIdx.x * 256 + threadIdx.x;
  if (idx >= dstRows * 512) return;
  int r = idx >> 9, cc = idx & 511;
  float v = (r < srcRows) ? src[(size_t)r * srcStride + colOff + cc] : 0.f;
  dst[idx] = f2bf(v);
}

// ---------------------------------------------------------------------------
// Pack weights once per call:
//  Wb3[2048][1024] = [W_hh | W_ih[:,512:1024]]   (fp32, recurrent GEMM)
//  dec_Wt[512][512] = dec_W^T                    (k-major)
//  bsum[2048] = b_ih + b_hh
// ---------------------------------------------------------------------------
__global__ __launch_bounds__(256) void build_weights(
    const float* __restrict__ W_ih, const float* __restrict__ W_hh,
    const float* __restrict__ dec_W, const float* __restrict__ b_ih,
    const float* __restrict__ b_hh, float* __restrict__ Wb3,
    float* __restrict__ dec_Wt, float* __restrict__ bsum) {
  int idx = blockIdx.x * 256 + threadIdx.x;
  if (idx < 2048 * 1024) {
    int n = idx >> 10, k = idx & 1023;
    Wb3[idx] = (k < 512) ? W_hh[(size_t)n * 512 + k]
                         : W_ih[(size_t)n * 1024 + 512 + (k - 512)];
  }
  if (idx < 512 * 512) {
    int k = idx >> 9, j = idx & 511;
    dec_Wt[idx] = dec_W[(size_t)j * 512 + k];
  }
  if (idx < 2048) bsum[idx] = b_ih[idx] + b_hh[idx];
}

// ---------------------------------------------------------------------------
// Gather embeddings -> bf16, rows m = t*64+b, zero pad rows 1216..1279
// ---------------------------------------------------------------------------
__global__ __launch_bounds__(256) void gather_emb(
    const float* __restrict__ emb, const int* __restrict__ captions,
    unsigned short* __restrict__ embx) {
  int m = blockIdx.x;
  int tid = threadIdx.x;
  if (m >= 1216) {
    embx[(size_t)m * 512 + tid] = 0;
    embx[(size_t)m * 512 + 256 + tid] = 0;
    return;
  }
  int t = m >> 6, b = m & 63;
  int cap = captions[b * LL + t];
#pragma unroll
  for (int i = 0; i < 2; ++i) {
    float v = emb[(size_t)cap * 512 + i * 256 + tid];
    embx[(size_t)m * 512 + i * 256 + tid] = f2bf(v);
  }
}

__global__ __launch_bounds__(256) void zero_t0_kernel(float* __restrict__ out) {
  int idx = blockIdx.x * 256 + threadIdx.x;
  if (idx < B * VV) {
    int b = idx / VV, v = idx % VV;
    out[(size_t)b * ((size_t)LL * VV) + v] = 0.f;
  }
}

// ---------------------------------------------------------------------------
// Persistent cooperative kernel: the entire 19-step recurrent loop.
// Grid = 256 blocks x 256 threads (1 block/CU, co-resident). 4 grid syncs/step.
// Block role: g = bid&3 (slice within batch), b = bid>>2 (batch element),
// except S3 where all 256 blocks tile the batched gates GEMM.
//   S0: LSTM pointwise (redundant per 4-block group; g0 writes c/hb/xcat-h)
//       + dec slice (128 cols, K split 2-way in-block)
//   S1: raw attention scores (49 n's per block)
//   S2: softmax (redundant per group, 784 B) + ctx slice (128 cols)
//   S3: gates_r[64][2048] = xcat @ Wb3^T, complete K (fp32 weights)
// Epilogue: h_19 -> hb block 18.
// ---------------------------------------------------------------------------
struct LoopArgs {
  const unsigned short* enc_projb;  // [64*196][512] bf16
  const unsigned short* encOutb;    // [64*196][512] bf16
  const float* dec_Wt;              // [512][512] k-major
  const float* dec_b;               // [512]
  const float* eW;                  // [512]
  const float* eb;                  // [1]
  const float* gates_x;             // [19*64][2048] input-part + bsum
  const float* Wb3;                 // [2048][1024] fp32
  float* gates_r;                   // [64][2048]
  float* c2;                        // [2][64][512] ping-pong cell state
  float* xcat;                      // [64][1024] (h | ctx)
  float* dec_buf;                   // [64][512]
  float* sw_raw;                    // [64][256]
  unsigned short* hb;               // [1280][512] bf16 h history
};

__global__ __launch_bounds__(256) void decoder_loop(LoopArgs A) {
  cg::grid_group grid = cg::this_grid();
  const int bid = blockIdx.x;
  const int tid = threadIdx.x;
  const int g = bid & 3;
  const int b = bid >> 2;
  const int lane = tid & 63;
  const int wvi = tid >> 6;

  __shared__ float hs[512];
  __shared__ float sdec[256];
  __shared__ float red[256];
  __shared__ float swl[256];
  __shared__ float cpb[512];
  __shared__ float xs[16][1028];  // +4 pad: breaks 16-way bank conflict

  for (int s = 0; s < 19; ++s) {
    // ---------------- S0: pointwise + dec slice ----------------
    {
      const int j0 = tid, j1 = tid + 256;
      float hn0, hn1;
      if (s == 0) {
        hn0 = hn1 = 0.f;
      } else {
        const float* gx = A.gates_x + ((size_t)(s - 1) * 64 + b) * 2048;
        const float* gr = A.gates_r + (size_t)b * 2048;
        const float* cold = A.c2 + (size_t)((s - 1) & 1) * 32768 + (size_t)b * 512;
        float* cnew = A.c2 + (size_t)(s & 1) * 32768 + (size_t)b * 512;
        float ig0 = gx[j0] + gr[j0];
        float fg0 = gx[512 + j0] + gr[512 + j0];
        float gg0 = gx[1024 + j0] + gr[1024 + j0];
        float og0 = gx[1536 + j0] + gr[1536 + j0];
        float cn0 = sigmoid_fast(fg0) * cold[j0] + sigmoid_fast(ig0) * tanh_fast(gg0);
        hn0 = sigmoid_fast(og0) * tanh_fast(cn0);
        float ig1 = gx[j1] + gr[j1];
        float fg1 = gx[512 + j1] + gr[512 + j1];
        float gg1 = gx[1024 + j1] + gr[1024 + j1];
        float og1 = gx[1536 + j1] + gr[1536 + j1];
        float cn1 = sigmoid_fast(fg1) * cold[j1] + sigmoid_fast(ig1) * tanh_fast(gg1);
        hn1 = sigmoid_fast(og1) * tanh_fast(cn1);
        if (g == 0) {
          cnew[j0] = cn0;
          cnew[j1] = cn1;
          unsigned short* hr = A.hb + ((size_t)(s - 1) * 64 + b) * 512;
          hr[j0] = f2bf(hn0);
          hr[j1] = f2bf(hn1);
        }
      }
      hs[j0] = hn0;
      hs[j1] = hn1;
      if (g == 0) {
        A.xcat[(size_t)b * 1024 + j0] = hn0;
        A.xcat[(size_t)b * 1024 + j1] = hn1;
      }
      __syncthreads();
      // dec slice: cols a = g*128 + cc; K split across kh in {0,1}
      const int cc = tid & 127, kh = tid >> 7;
      const int a = g * 128 + cc;
      float acc = 0.f;
      const float* W = A.dec_Wt + (size_t)(kh * 256) * 512 + a;
      const float* hp = &hs[kh * 256];
#pragma unroll 8
      for (int k = 0; k < 256; ++k) acc += hp[k] * W[(size_t)k * 512];
      sdec[tid] = acc;
      __syncthreads();
      if (tid < 128) {
        A.dec_buf[(size_t)b * 512 + a] = sdec[tid] + sdec[tid + 128] + A.dec_b[a];
      }
    }
    grid.sync();

    // ---------------- S1: raw scores ----------------
    {
      float ew8[8], sd8[8];
      const float* db = A.dec_buf + (size_t)b * 512;
#pragma unroll
      for (int j = 0; j < 8; ++j) {
        ew8[j] = A.eW[lane * 8 + j];
        sd8[j] = db[lane * 8 + j];
      }
      float eb0 = A.eb[0];
      const int n0 = g * 49;
      for (int i = wvi; i < 49; i += 4) {
        int n = n0 + i;
        const unsigned short* ep =
            A.enc_projb + ((size_t)b * NN + n) * 512 + lane * 8;
        bf16x8 v8 = *(const bf16x8*)ep;
        float a2 = 0.f;
#pragma unroll
        for (int j = 0; j < 8; ++j)
          a2 += tanh_fast(bf2f((unsigned short)v8[j]) + sd8[j]) * ew8[j];
#pragma unroll
        for (int off = 32; off; off >>= 1) a2 += __shfl_down(a2, off, 64);
        if (lane == 0) A.sw_raw[(size_t)b * 256 + n] = a2 + eb0;
      }
    }
    grid.sync();

    // ---------------- S2: softmax (redundant) + ctx slice ----------------
    {
      float v = (tid < NN) ? A.sw_raw[(size_t)b * 256 + tid] : -1e30f;
      red[tid] = v;
      __syncthreads();
      for (int st = 128; st; st >>= 1) {
        if (tid < st) red[tid] = fmaxf(red[tid], red[tid + st]);
        __syncthreads();
      }
      float mx = red[0];
      __syncthreads();
      float e = (tid < NN) ? __expf(v - mx) : 0.f;
      red[tid] = e;
      __syncthreads();
      for (int st = 128; st; st >>= 1) {
        if (tid < st) red[tid] += red[tid + st];
        __syncthreads();
      }
      float inv = 1.f / red[0];
      if (tid < NN) swl[tid] = e * inv;
      __syncthreads();
      // ctx slice cols a0 = g*128; 2 cols per lane via uint loads
      const unsigned short* eo =
          A.encOutb + (size_t)b * NN * 512 + g * 128 + lane * 2;
      float a0 = 0.f, a1 = 0.f;
      for (int n = wvi; n < NN; n += 4) {
        float w = swl[n];
        unsigned u = *(const unsigned*)(eo + (size_t)n * 512);
        a0 += w * __uint_as_float((u & 0xffffu) << 16);
        a1 += w * __uint_as_float((u >> 16) << 16);
      }
      cpb[wvi * 128 + lane * 2] = a0;
      cpb[wvi * 128 + lane * 2 + 1] = a1;
      __syncthreads();
      if (tid < 128) {
        float cv = cpb[tid] + cpb[128 + tid] + cpb[256 + tid] + cpb[384 + tid];
        A.xcat[(size_t)b * 1024 + 512 + g * 128 + tid] = cv;
      }
    }
    grid.sync();

    // ---------------- S3: gates_r = xcat @ Wb3^T (batched) ----------------
    {
      const int outIdx = tid & 127;       // nsub(8) x bsub(16)
      const int kh = tid >> 7;            // K half
      const int nsub = outIdx >> 4, bsub = outIdx & 15;
      const int n = bid * 8 + nsub;
      for (int bc = 0; bc < 4; ++bc) {
        __syncthreads();
        for (int e2 = tid; e2 < 16 * 256; e2 += 256) {
          int rr = e2 >> 8, c4 = e2 & 255;
          *(float4*)&xs[rr][c4 * 4] =
              *(const float4*)(A.xcat + (size_t)(bc * 16 + rr) * 1024 + c4 * 4);
        }
        __syncthreads();
        const float* wr = A.Wb3 + (size_t)n * 1024 + kh * 512;
        const float* xr = &xs[bsub][kh * 512];
        float acc = 0.f;
#pragma unroll 8
        for (int k4 = 0; k4 < 128; ++k4) {
          float4 w4 = *(const float4*)(wr + k4 * 4);
          float4 x4 = *(const float4*)(xr + k4 * 4);
          acc += w4.x * x4.x + w4.y * x4.y + w4.z * x4.z + w4.w * x4.w;
        }
        red[tid] = acc;
        __syncthreads();
        if (tid < 128) {
          int bglob = bc * 16 + bsub;
          A.gates_r[(size_t)bglob * 2048 + n] = red[tid] + red[tid + 128];
        }
      }
    }
    grid.sync();
  }

  // ---------------- epilogue: h_19 -> hb block 18 ----------------
  if (g == 0) {
    const float* gx = A.gates_x + ((size_t)18 * 64 + b) * 2048;
    const float* gr = A.gates_r + (size_t)b * 2048;
    const float* cold = A.c2 + (size_t)(18 & 1) * 32768 + (size_t)b * 512;
    unsigned short* hr = A.hb + ((size_t)18 * 64 + b) * 512;
    for (int j = tid; j < 512; j += 256) {
      float ig = gx[j] + gr[j];
      float fg = gx[512 + j] + gr[512 + j];
      float gg = gx[1024 + j] + gr[1024 + j];
      float og = gx[1536 + j] + gr[1536 + j];
      float cn = sigmoid_fast(fg) * cold[j] + sigmoid_fast(ig) * tanh_fast(gg);
      float hn = sigmoid_fast(og) * tanh_fast(cn);
      hr[j] = f2bf(hn);
    }
  }
}

extern "C" void kernel_launch(void* const* d_in, const int* in_sizes, int n_in,
                              void* d_out, int out_size, void* d_ws, size_t ws_size,
                              hipStream_t stream) {
  const float* enc_out  = (const float*)d_in[0];
  const int*   captions = (const int*)d_in[1];
  const float* emb      = (const float*)d_in[2];
  const float* W_ih     = (const float*)d_in[3];
  const float* W_hh     = (const float*)d_in[4];
  const float* b_ih     = (const float*)d_in[5];
  const float* b_hh     = (const float*)d_in[6];
  const float* enc_W    = (const float*)d_in[7];
  const float* enc_b    = (const float*)d_in[8];
  const float* dec_W    = (const float*)d_in[9];
  const float* dec_b    = (const float*)d_in[10];
  const float* energy_W = (const float*)d_in[11];
  const float* energy_b = (const float*)d_in[12];
  const float* fc_W     = (const float*)d_in[13];
  const float* fc_b     = (const float*)d_in[14];
  float* out = (float*)d_out;

  // Workspace layout
  float* ws = (float*)d_ws;
  float* c2         = ws;                                   // 2*64*512
  float* xcat       = c2 + 2 * 32768;                       // 64*1024
  float* dec_buf    = xcat + 65536;                         // 64*512
  float* sw_raw     = dec_buf + 32768;                      // 64*256
  float* gates_all  = sw_raw + 16384;                       // 19*64*2048
  float* gates_r    = gates_all + (size_t)19 * 131072;      // 64*2048
  float* Wb3        = gates_r + 131072;                     // 2048*1024
  float* dec_Wt     = Wb3 + (size_t)2048 * 1024;            // 512*512
  float* bsum       = dec_Wt + 262144;                      // 2048
  unsigned short* enc_projb = (unsigned short*)(bsum + 2048); // 12544*512
  unsigned short* fcWb    = enc_projb + (size_t)12544 * 512;  // 20096*512
  unsigned short* encWb   = fcWb + (size_t)20096 * 512;       // 512*512
  unsigned short* encOutb = encWb + (size_t)512 * 512;        // 12544*512
  unsigned short* Wb0b    = encOutb + (size_t)12544 * 512;    // 2048*512
  unsigned short* embxb   = Wb0b + (size_t)2048 * 512;        // 1280*512
  unsigned short* hb      = embxb + (size_t)1280 * 512;       // 1280*512

  hipMemsetAsync(c2, 0, 32768 * sizeof(float), stream);  // c_0 = 0 (buffer 0)
  hipMemsetAsync(hb + (size_t)1216 * 512, 0,
                 (size_t)64 * 512 * sizeof(unsigned short), stream);
  zero_t0_kernel<<<(B * VV + 255) / 256, 256, 0, stream>>>(out);

  build_weights<<<(2048 * 1024) / 256, 256, 0, stream>>>(
      W_ih, W_hh, dec_W, b_ih, b_hh, Wb3, dec_Wt, bsum);

  convert_pad<<<(20096 * 512) / 256, 256, 0, stream>>>(fc_W, fcWb, 20000, 20096, 512, 0);
  convert_pad<<<(512 * 512) / 256, 256, 0, stream>>>(enc_W, encWb, 512, 512, 512, 0);
  convert_pad<<<(12544 * 512) / 256, 256, 0, stream>>>(enc_out, encOutb, 12544, 12544, 512, 0);
  convert_pad<<<(2048 * 512) / 256, 256, 0, stream>>>(W_ih, Wb0b, 2048, 2048, 1024, 0);

  gather_emb<<<1280, 256, 0, stream>>>(emb, captions, embxb);

  // gates_x[t*64+b, :] = embx @ W_ih[:, :512]^T + (b_ih + b_hh)   [MFMA]
  gemm_mfma_bt<<<dim3(16, 10), 256, 0, stream>>>(
      embxb, Wb0b, bsum, gates_all, 1216, 2048, 512, 2048, 0, 0);

  // enc_projb (bf16) = enc_out @ enc_W^T + enc_b   [MFMA, bf16 store]
  gemm_mfma_bt<<<dim3(4, 98), 256, 0, stream>>>(
      encOutb, encWb, enc_b, (float*)enc_projb, 12544, 512, 512, 512, 2, 0);

  // Entire 19-step recurrent loop: one persistent cooperative kernel.
  LoopArgs la;
  la.enc_projb = enc_projb;
  la.encOutb = encOutb;
  la.dec_Wt = dec_Wt;
  la.dec_b = dec_b;
  la.eW = energy_W;
  la.eb = energy_b;
  la.gates_x = gates_all;
  la.Wb3 = Wb3;
  la.gates_r = gates_r;
  la.c2 = c2;
  la.xcat = xcat;
  la.dec_buf = dec_buf;
  la.sw_raw = sw_raw;
  la.hb = hb;
  void* kargs[] = {(void*)&la};
  hipLaunchCooperativeKernel((void*)decoder_loop, dim3(256), dim3(256), kargs,
                             0, stream);

  // Batched logits: out[b, t+1, :] = h @ fc_W^T + fc_b   [MFMA, scatter]
  // gridMX=1: m-major block order so fcWb (20.6 MB) streams once through L2.
  gemm_mfma_bt<<<dim3(10, 157), 256, 0, stream>>>(
      hb, fcWb, fc_b, out, 1216, 20000, 512, 0, 1, 1);
}

// Round 3
// 1593.546 us; speedup vs baseline: 2.3776x; 2.3776x over previous
//
#include <hip/hip_runtime.h>
#include <hip/hip_bf16.h>
#include <math.h>

// Problem dims (fixed)
#define B   64
#define NN  196
#define HH  512
#define EE  512
#define AA  512
#define VV  20000
#define LL  20

#define TM 64
#define TN 64
#define TK 16

typedef __attribute__((ext_vector_type(8))) short bf16x8;
typedef __attribute__((ext_vector_type(4))) float floatx4;

__device__ __forceinline__ float tanh_fast(float x) {
  float e2 = __expf(2.f * x);
  return 1.f - 2.f / (e2 + 1.f);
}
__device__ __forceinline__ float sigmoid_fast(float x) {
  return 1.f / (1.f + __expf(-x));
}
__device__ __forceinline__ float bf2f(unsigned short u) {
  return __uint_as_float(((unsigned)u) << 16);
}
__device__ __forceinline__ unsigned short f2bf(float v) {
  __hip_bfloat16 h = __float2bfloat16(v);
  return *reinterpret_cast<unsigned short*>(&h);
}

// ---------------------------------------------------------------------------
// bf16 MFMA GEMM: C[M,N] = Xb[M,K](bf16) @ Wb[N,K](bf16)^T + bias
// 128x128 tile, BK=32, 256 threads = 4 waves, each wave 64x64 via 16 MFMAs.
// gridMX: 0 -> (x=n-tiles, y=m-tiles); 1 -> (x=m-tiles, y=n-tiles).
//   gridMX=1: consecutive blocks share one B-panel so a huge B (fcWb 20.6MB)
//   streams through L2 once instead of ~5x.
// outMode==0: fp32 C[m*ldC+n]
// outMode==1: logits scatter out[b, t+1, n] with m = t*64 + b.
// outMode==2: bf16 store ((ushort*)C)[m*ldC+n]
// NOTE: A-tile rows beyond M are read (must be allocated) but their products
// only land in masked-out output rows — garbage content is safe.
// ---------------------------------------------------------------------------
__global__ __launch_bounds__(256) void gemm_mfma_bt(
    const unsigned short* __restrict__ Xb, const unsigned short* __restrict__ Wb,
    const float* __restrict__ bias, float* __restrict__ C,
    int M, int N, int K, int ldC, int outMode, int gridMX) {
  __shared__ unsigned short As[128 * 32];
  __shared__ unsigned short Bs[128 * 32];
  const int tid = threadIdx.x;
  const int lane = tid & 63;
  const int l15 = lane & 15;
  const int q = lane >> 4;        // quad 0..3
  const int wv = tid >> 6;        // wave 0..3
  const int wm = (wv >> 1) * 64;  // wave m-offset in tile
  const int wn = (wv & 1) * 64;   // wave n-offset in tile
  const int mBase = (gridMX ? blockIdx.x : blockIdx.y) * 128;
  const int nBase = (gridMX ? blockIdx.y : blockIdx.x) * 128;

  const int c0 = tid, c1 = tid + 256;
  const int r0 = c0 >> 2, o0 = (c0 & 3) * 8;
  const int r1 = c1 >> 2, o1 = (c1 & 3) * 8;

  floatx4 zero = {0.f, 0.f, 0.f, 0.f};
  floatx4 acc[4][4];
#pragma unroll
  for (int i = 0; i < 4; ++i)
#pragma unroll
    for (int j = 0; j < 4; ++j) acc[i][j] = zero;

  for (int k0 = 0; k0 < K; k0 += 32) {
    uint4 a0 = *(const uint4*)(Xb + (size_t)(mBase + r0) * K + k0 + o0);
    uint4 a1 = *(const uint4*)(Xb + (size_t)(mBase + r1) * K + k0 + o1);
    uint4 b0 = *(const uint4*)(Wb + (size_t)(nBase + r0) * K + k0 + o0);
    uint4 b1 = *(const uint4*)(Wb + (size_t)(nBase + r1) * K + k0 + o1);
    __syncthreads();
    *(uint4*)&As[c0 * 8] = a0;
    *(uint4*)&As[c1 * 8] = a1;
    *(uint4*)&Bs[c0 * 8] = b0;
    *(uint4*)&Bs[c1 * 8] = b1;
    __syncthreads();
    bf16x8 af[4], bfv[4];
#pragma unroll
    for (int i = 0; i < 4; ++i)
      af[i] = *(const bf16x8*)&As[(wm + i * 16 + l15) * 32 + q * 8];
#pragma unroll
    for (int j = 0; j < 4; ++j)
      bfv[j] = *(const bf16x8*)&Bs[(wn + j * 16 + l15) * 32 + q * 8];
#pragma unroll
    for (int i = 0; i < 4; ++i)
#pragma unroll
      for (int j = 0; j < 4; ++j)
        acc[i][j] = __builtin_amdgcn_mfma_f32_16x16x32_bf16(af[i], bfv[j],
                                                            acc[i][j], 0, 0, 0);
  }

#pragma unroll
  for (int i = 0; i < 4; ++i) {
#pragma unroll
    for (int j = 0; j < 4; ++j) {
#pragma unroll
      for (int p = 0; p < 4; ++p) {
        int m = mBase + wm + i * 16 + q * 4 + p;
        int n = nBase + wn + j * 16 + l15;
        if (m < M && n < N) {
          float v = acc[i][j][p];
          if (bias) v += bias[n];
          if (outMode == 1) {
            size_t idx = (size_t)(m & 63) * ((size_t)LL * VV) +
                         (size_t)((m >> 6) + 1) * VV + n;
            C[idx] = v;
          } else if (outMode == 2) {
            ((unsigned short*)C)[(size_t)m * ldC + n] = f2bf(v);
          } else {
            C[(size_t)m * ldC + n] = v;
          }
        }
      }
    }
  }
}

// ---------------------------------------------------------------------------
// fp32 -> bf16 conversion with optional row padding (zero fill) and stride.
// ---------------------------------------------------------------------------
__global__ __launch_bounds__(256) void convert_pad(
    const float* __restrict__ src, unsigned short* __restrict__ dst,
    int srcRows, int dstRows, int srcStride, int colOff) {
  int idx = blockIdx.x * 256 + threadIdx.x;
  if (idx >= dstRows * 512) return;
  int r = idx >> 9, cc = idx & 511;
  float v = (r < srcRows) ? src[(size_t)r * srcStride + colOff + cc] : 0.f;
  dst[idx] = f2bf(v);
}

// ---------------------------------------------------------------------------
// Skinny GEMM, M=64, split-K, plain stores to per-split partial buffers.
// X[64,K] fp32, W[N,K] fp32. grid = (N/64, splitK). No atomics.
// ---------------------------------------------------------------------------
__global__ __launch_bounds__(256) void gemm_skinny(
    const float* __restrict__ X, const float* __restrict__ W,
    float* __restrict__ part, int K, int Ks) {
  __shared__ float Xs[TK][TM + 4];
  __shared__ float Ws[TK][TN + 4];
  const int nBase = blockIdx.x * TN;
  const int kBase = blockIdx.y * Ks;
  const int tid = threadIdx.x;
  const int tx = tid & 15;
  const int ty = tid >> 4;
  float acc[4][4] = {};

  for (int k0 = kBase; k0 < kBase + Ks; k0 += TK) {
#pragma unroll
    for (int i = 0; i < 4; ++i) {
      int e = tid + i * 256;
      int r = e >> 4;
      int cc = e & 15;
      Xs[cc][r] = X[(size_t)r * K + k0 + cc];
      Ws[cc][r] = W[(size_t)(nBase + r) * K + k0 + cc];
    }
    __syncthreads();
#pragma unroll
    for (int kk = 0; kk < TK; ++kk) {
      float xv[4], wvv[4];
#pragma unroll
      for (int i = 0; i < 4; ++i) xv[i] = Xs[kk][ty * 4 + i];
#pragma unroll
      for (int j = 0; j < 4; ++j) wvv[j] = Ws[kk][tx * 4 + j];
#pragma unroll
      for (int i = 0; i < 4; ++i)
#pragma unroll
        for (int j = 0; j < 4; ++j) acc[i][j] += xv[i] * wvv[j];
    }
    __syncthreads();
  }

  float* o = part + (size_t)blockIdx.y * (64 * 2048);
#pragma unroll
  for (int i = 0; i < 4; ++i) {
    int m = ty * 4 + i;
    float4 r4;
    r4.x = acc[i][0]; r4.y = acc[i][1]; r4.z = acc[i][2]; r4.w = acc[i][3];
    *(float4*)(o + (size_t)m * 2048 + nBase + tx * 4) = r4;
  }
}

// ---------------------------------------------------------------------------
// Pack weights once per call:
//  Wb3[2048][1024] = [W_hh | W_ih[:,512:1024]]   (fp32, recurrent GEMM)
//  bsum[2048] = b_ih + b_hh
// ---------------------------------------------------------------------------
__global__ __launch_bounds__(256) void build_weights(
    const float* __restrict__ W_ih, const float* __restrict__ W_hh,
    const float* __restrict__ b_ih, const float* __restrict__ b_hh,
    float* __restrict__ Wb3, float* __restrict__ bsum) {
  int idx = blockIdx.x * 256 + threadIdx.x;
  if (idx < 2048 * 1024) {
    int n = idx >> 10, k = idx & 1023;
    Wb3[idx] = (k < 512) ? W_hh[(size_t)n * 512 + k]
                         : W_ih[(size_t)n * 1024 + 512 + (k - 512)];
  }
  if (idx < 2048) bsum[idx] = b_ih[idx] + b_hh[idx];
}

// ---------------------------------------------------------------------------
// Gather embeddings -> bf16, rows m = t*64+b, zero pad rows 1216..1279
// ---------------------------------------------------------------------------
__global__ __launch_bounds__(256) void gather_emb(
    const float* __restrict__ emb, const int* __restrict__ captions,
    unsigned short* __restrict__ embx) {
  int m = blockIdx.x;
  int tid = threadIdx.x;
  if (m >= 1216) {
    embx[(size_t)m * 512 + tid] = 0;
    embx[(size_t)m * 512 + 256 + tid] = 0;
    return;
  }
  int t = m >> 6, b = m & 63;
  int cap = captions[b * LL + t];
#pragma unroll
  for (int i = 0; i < 2; ++i) {
    float v = emb[(size_t)cap * 512 + i * 256 + tid];
    embx[(size_t)m * 512 + i * 256 + tid] = f2bf(v);
  }
}

__global__ __launch_bounds__(256) void zero_t0_kernel(float* __restrict__ out) {
  int idx = blockIdx.x * 256 + threadIdx.x;
  if (idx < B * VV) {
    int b = idx / VV, v = idx % VV;
    out[(size_t)b * ((size_t)LL * VV) + v] = 0.f;
  }
}

// ---------------------------------------------------------------------------
// LSTM pointwise for step s: h_s from gates_{s-1} (base + 8 split-K partials).
// Writes: c (in place), hbt bf16 [64+pad][512] (dec GEMM A operand),
//         hb slot s-1 (bf16 history for logits), xcat h-half (fp32, skinny A).
// isFirst: h_0 = 0 (c untouched, no hb write).
// ---------------------------------------------------------------------------
__global__ __launch_bounds__(256) void lstm_pointwise2(
    const float* __restrict__ gates_base, const float* __restrict__ gates_part,
    float* __restrict__ c, float* __restrict__ xcat,
    unsigned short* __restrict__ hbt, unsigned short* __restrict__ hb_row,
    int isFirst) {
  int idx = blockIdx.x * 256 + threadIdx.x;  // 0 .. 64*512
  int b = idx >> 9, j = idx & 511;
  float hn;
  if (isFirst) {
    hn = 0.f;
  } else {
    const float* gb = gates_base + (size_t)b * 2048;
    const float* gp = gates_part + (size_t)b * 2048;
    float ig = gb[j], fg = gb[512 + j], gg = gb[1024 + j], og = gb[1536 + j];
#pragma unroll
    for (int s = 0; s < 8; ++s) {
      const float* p = gp + (size_t)s * (64 * 2048);
      ig += p[j];
      fg += p[512 + j];
      gg += p[1024 + j];
      og += p[1536 + j];
    }
    float cn = sigmoid_fast(fg) * c[idx] + sigmoid_fast(ig) * tanh_fast(gg);
    hn = sigmoid_fast(og) * tanh_fast(cn);
    c[idx] = cn;
    hb_row[idx] = f2bf(hn);
  }
  hbt[idx] = f2bf(hn);
  xcat[(size_t)b * 1024 + j] = hn;
}

// ---------------------------------------------------------------------------
// Attention scores + softmax + context (one block of 512 thr per b).
//   scores_n = tanh(enc_projb[b,n,:] + dec_buf[b,:]) . eW + eb  (bf16 reads)
//   softmax over N; ctx = attw @ encOutb -> xcat[:, 512:1024]
// ---------------------------------------------------------------------------
__global__ __launch_bounds__(512) void attn_score_ctx(
    const unsigned short* __restrict__ enc_projb,
    const unsigned short* __restrict__ encOutb,
    const float* __restrict__ dec_buf, const float* __restrict__ eW,
    const float* __restrict__ eb, float* __restrict__ xcat) {
  int b = blockIdx.x;
  int tid = threadIdx.x;
  __shared__ float sw[NN];
  __shared__ float tmp[256];
  __shared__ float cp[1024];

  int wvv = tid >> 6, lane = tid & 63;
  float ew8[8], sd8[8];
  const float* db = dec_buf + (size_t)b * 512;
#pragma unroll
  for (int j = 0; j < 8; ++j) {
    ew8[j] = eW[lane * 8 + j];
    sd8[j] = db[lane * 8 + j];
  }
  float eb0 = eb[0];
  for (int n = wvv; n < NN; n += 8) {
    const unsigned short* ep = enc_projb + ((size_t)b * NN + n) * 512 + lane * 8;
    bf16x8 v8 = *(const bf16x8*)ep;
    float a = 0.f;
#pragma unroll
    for (int j = 0; j < 8; ++j)
      a += tanh_fast(bf2f((unsigned short)v8[j]) + sd8[j]) * ew8[j];
#pragma unroll
    for (int off = 32; off; off >>= 1) a += __shfl_down(a, off, 64);
    if (lane == 0) sw[n] = a + eb0;
  }
  __syncthreads();

  // softmax over N
  float v = (tid < NN) ? sw[tid] : -1e30f;
  if (tid < 256) tmp[tid] = v;
  __syncthreads();
  for (int s = 128; s; s >>= 1) {
    if (tid < s) tmp[tid] = fmaxf(tmp[tid], tmp[tid + s]);
    __syncthreads();
  }
  float mx = tmp[0];
  __syncthreads();
  float e = (tid < NN) ? __expf(v - mx) : 0.f;
  if (tid < 256) tmp[tid] = e;
  __syncthreads();
  for (int s = 128; s; s >>= 1) {
    if (tid < s) tmp[tid] += tmp[tid + s];
    __syncthreads();
  }
  float inv = 1.f / tmp[0];
  if (tid < NN) sw[tid] = e * inv;
  __syncthreads();

  // context: bf16 enc_out, uint loads, n split across thread halves,
  // unroll 7 (98 = 14*7) for load-latency ILP.
  int half = tid >> 8, hp = tid & 255;
  const unsigned short* eo = encOutb + (size_t)b * NN * 512 + hp * 2;
  float a0 = 0.f, a1 = 0.f;
  int n0 = half * 98;
#pragma unroll 7
  for (int n = n0; n < n0 + 98; ++n) {
    float w = sw[n];
    unsigned u = *(const unsigned*)(eo + (size_t)n * 512);
    a0 += w * __uint_as_float((u & 0xffffu) << 16);
    a1 += w * __uint_as_float((u >> 16) << 16);
  }
  cp[half * 512 + hp * 2] = a0;
  cp[half * 512 + hp * 2 + 1] = a1;
  __syncthreads();
  xcat[(size_t)b * 1024 + 512 + tid] = cp[tid] + cp[512 + tid];
}

// ---------------------------------------------------------------------------
// Final h_19 from gates_18 (base + partials) -> hb rows 1152..1215 (bf16)
// ---------------------------------------------------------------------------
__global__ __launch_bounds__(256) void final_h(
    const float* __restrict__ gates_base, const float* __restrict__ gates_part,
    const float* __restrict__ c, unsigned short* __restrict__ hb19) {
  int idx = blockIdx.x * 256 + threadIdx.x;  // 0 .. 64*512
  int b = idx >> 9, j = idx & 511;
  const float* gb = gates_base + (size_t)b * 2048;
  const float* gp = gates_part + (size_t)b * 2048;
  float ig = gb[j], fg = gb[512 + j], gg = gb[1024 + j], og = gb[1536 + j];
#pragma unroll
  for (int s = 0; s < 8; ++s) {
    const float* p = gp + (size_t)s * (64 * 2048);
    ig += p[j];
    fg += p[512 + j];
    gg += p[1024 + j];
    og += p[1536 + j];
  }
  float cn = sigmoid_fast(fg) * c[idx] + sigmoid_fast(ig) * tanh_fast(gg);
  float hn = sigmoid_fast(og) * tanh_fast(cn);
  hb19[idx] = f2bf(hn);
}

extern "C" void kernel_launch(void* const* d_in, const int* in_sizes, int n_in,
                              void* d_out, int out_size, void* d_ws, size_t ws_size,
                              hipStream_t stream) {
  const float* enc_out  = (const float*)d_in[0];
  const int*   captions = (const int*)d_in[1];
  const float* emb      = (const float*)d_in[2];
  const float* W_ih     = (const float*)d_in[3];
  const float* W_hh     = (const float*)d_in[4];
  const float* b_ih     = (const float*)d_in[5];
  const float* b_hh     = (const float*)d_in[6];
  const float* enc_W    = (const float*)d_in[7];
  const float* enc_b    = (const float*)d_in[8];
  const float* dec_W    = (const float*)d_in[9];
  const float* dec_b    = (const float*)d_in[10];
  const float* energy_W = (const float*)d_in[11];
  const float* energy_b = (const float*)d_in[12];
  const float* fc_W     = (const float*)d_in[13];
  const float* fc_b     = (const float*)d_in[14];
  float* out = (float*)d_out;

  // Workspace layout
  float* ws = (float*)d_ws;
  float* c          = ws;                                   // 64*512
  float* xcat       = c + 32768;                            // 64*1024
  float* dec_buf    = xcat + 65536;                         // 64*512
  float* gates_all  = dec_buf + 32768;                      // 19*64*2048
  float* gates_part = gates_all + (size_t)19 * 131072;      // 8*64*2048
  float* Wb3        = gates_part + (size_t)8 * 131072;      // 2048*1024
  float* bsum       = Wb3 + (size_t)2048 * 1024;            // 2048
  unsigned short* enc_projb = (unsigned short*)(bsum + 2048); // 12544*512
  unsigned short* fcWb    = enc_projb + (size_t)12544 * 512;  // 20096*512
  unsigned short* encWb   = fcWb + (size_t)20096 * 512;       // 512*512
  unsigned short* encOutb = encWb + (size_t)512 * 512;        // 12544*512
  unsigned short* Wb0b    = encOutb + (size_t)12544 * 512;    // 2048*512
  unsigned short* dec_Wb  = Wb0b + (size_t)2048 * 512;        // 512*512
  unsigned short* embxb   = dec_Wb + (size_t)512 * 512;       // 1280*512
  unsigned short* hb      = embxb + (size_t)1280 * 512;       // 1280*512
  unsigned short* hbt     = hb + (size_t)1280 * 512;          // 128*512 (A op)

  hipMemsetAsync(c, 0, 32768 * sizeof(float), stream);
  hipMemsetAsync(hb + (size_t)1216 * 512, 0,
                 (size_t)64 * 512 * sizeof(unsigned short), stream);
  zero_t0_kernel<<<(B * VV + 255) / 256, 256, 0, stream>>>(out);

  build_weights<<<(2048 * 1024) / 256, 256, 0, stream>>>(
      W_ih, W_hh, b_ih, b_hh, Wb3, bsum);

  convert_pad<<<(20096 * 512) / 256, 256, 0, stream>>>(fc_W, fcWb, 20000, 20096, 512, 0);
  convert_pad<<<(512 * 512) / 256, 256, 0, stream>>>(enc_W, encWb, 512, 512, 512, 0);
  convert_pad<<<(12544 * 512) / 256, 256, 0, stream>>>(enc_out, encOutb, 12544, 12544, 512, 0);
  convert_pad<<<(2048 * 512) / 256, 256, 0, stream>>>(W_ih, Wb0b, 2048, 2048, 1024, 0);
  convert_pad<<<(512 * 512) / 256, 256, 0, stream>>>(dec_W, dec_Wb, 512, 512, 512, 0);

  gather_emb<<<1280, 256, 0, stream>>>(emb, captions, embxb);

  // gates_x[t*64+b, :] = embx @ W_ih[:, :512]^T + (b_ih + b_hh)   [MFMA]
  gemm_mfma_bt<<<dim3(16, 10), 256, 0, stream>>>(
      embxb, Wb0b, bsum, gates_all, 1216, 2048, 512, 2048, 0, 0);

  // enc_projb (bf16) = enc_out @ enc_W^T + enc_b   [MFMA, bf16 store]
  gemm_mfma_bt<<<dim3(4, 98), 256, 0, stream>>>(
      encOutb, encWb, enc_b, (float*)enc_projb, 12544, 512, 512, 512, 2, 0);

  for (int s = 0; s < LL - 1; ++s) {
    // 1) pointwise: h_s (bf16 into hbt + hb slot s-1), c, xcat h-half
    lstm_pointwise2<<<(B * HH) / 256, 256, 0, stream>>>(
        s ? (gates_all + (size_t)(s - 1) * 131072) : nullptr, gates_part, c,
        xcat, hbt, hb + (size_t)(s > 0 ? s - 1 : 0) * 32768, s == 0 ? 1 : 0);

    // 2) dec = h_s @ dec_W^T + dec_b   [MFMA, 4 blocks, pad rows masked]
    gemm_mfma_bt<<<dim3(4, 1), 256, 0, stream>>>(
        hbt, dec_Wb, dec_b, dec_buf, 64, 512, 512, 512, 0, 0);

    // 3) scores + softmax + context
    attn_score_ctx<<<B, 512, 0, stream>>>(enc_projb, encOutb, dec_buf,
                                          energy_W, energy_b, xcat);

    // 4) gates partials: [h|ctx] @ [W_hh | W_ih_ctx]^T  (K=1024, splitK=8)
    gemm_skinny<<<dim3(2048 / TN, 8), 256, 0, stream>>>(xcat, Wb3, gates_part,
                                                        1024, 128);
  }

  // h_19 -> hb rows 1152..1215
  final_h<<<(B * HH) / 256, 256, 0, stream>>>(
      gates_all + (size_t)18 * 131072, gates_part, c, hb + (size_t)1152 * 512);

  // Batched logits: out[b, t+1, :] = h @ fc_W^T + fc_b   [MFMA, scatter]
  // gridMX=1: m-major order -> fcWb (20.6 MB) streams once.
  gemm_mfma_bt<<<dim3(10, 157), 256, 0, stream>>>(
      hb, fcWb, fc_b, out, 1216, 20000, 512, 0, 1, 1);
}